// Round 10
// baseline (59.292 us; speedup 1.0000x reference)
//
#include <hip/hip_runtime.h>
#include <hip/hip_bf16.h>

#define B_    512
#define F_    128
#define NTRIP 1024
#define MARGIN 1.0f
#define NBLK  32      // 512/16 pair-blocks per dim
#define NPB   528     // upper-tri pair-blocks
#define PREP  130     // prep blocks: 128 m/g + 2 triplet

// ws layout (float offsets)
#define OFF_M    0                 // m  [128][512]
#define OFF_MT   65536             // mT [512][128]
#define OFF_G    131072            // g  [128]
#define OFF_TL   131200            // tl [2]
#define OFF_SQ   131216            // sq [128] = sqrt(sqrt(S_ii))
#define OFF_PART 147600            // ushort[528*16384] (17.3 MB)

typedef __attribute__((ext_vector_type(8))) short bf16x8;
typedef __attribute__((ext_vector_type(4))) float f32x4;
typedef __attribute__((ext_vector_type(4))) unsigned int u32x4;

#define LDS_ROW 20    // dwords per 32-pair row: 16 + 4 pad (80 B) — 0-conflict
#define SL_ROW  136   // ushorts per slab-stage row (272 B, 16B-aligned, bank-spread)

__device__ inline unsigned int bf16r(float f) {   // RNE float->bf16 (f>=0, finite)
    unsigned int u = __float_as_uint(f);
    u += 0x7FFFu + ((u >> 16) & 1u);
    return u >> 16;
}

// ===== K1: blocks 0..527 pair GEMM; 528..657 prep (m/mT/g/sq/triplet) ======
__global__ __launch_bounds__(512)
void k1_prep_pair(const float* __restrict__ emb, const int* __restrict__ trip,
                  float* __restrict__ m, float* __restrict__ mT,
                  float* __restrict__ g, float* __restrict__ tl,
                  float* __restrict__ sq, float* __restrict__ out,
                  unsigned short* __restrict__ part) {
    __shared__ __align__(16) unsigned int dt[4 * F_ * LDS_ROW];   // 40 KB
    const int bid = blockIdx.x;
    const int t   = threadIdx.x;

    if (bid >= NPB) {
        const int pb = bid - NPB;
        if (pb < F_) {
            // ---- m/g/sq for feature i ----
            float*  x    = (float*)dt;                    // [512]
            float4* red4 = (float4*)((float*)dt + 512);   // [512] (8 KB)
            const int i = pb;
            if (i == 0 && t == 0) out[0] = 0.f;           // reset accumulator
            x[t] = emb[t * F_ + i];
            __syncthreads();
            const float xa = x[t];
            float s0 = 0.f, s1 = 0.f, s2 = 0.f, s3 = 0.f;
            for (int b = 0; b < B_; b += 4) {
                s0 += fabsf(xa - x[b]);
                s1 += fabsf(xa - x[b + 1]);
                s2 += fabsf(xa - x[b + 2]);
                s3 += fabsf(xa - x[b + 3]);
            }
            float s = (s0 + s1) + (s2 + s3);
            float mv = s * (1.f / B_);
            m[i * B_ + t]  = mv;
            mT[t * F_ + i] = mv;
            red4[t] = make_float4(s, xa, xa * xa, mv * mv);
            __syncthreads();
            for (int sh = 256; sh > 0; sh >>= 1) {
                if (t < sh) {
                    float4 a = red4[t], b = red4[t + sh];
                    red4[t] = make_float4(a.x + b.x, a.y + b.y, a.z + b.z, a.w + b.w);
                }
                __syncthreads();
            }
            if (t == 0) {
                float4 r = red4[0];
                const float Bf = (float)B_;
                float gi = r.x * (1.f / (Bf * Bf));
                g[i] = gi;
                float DD  = 2.f * Bf * r.z - 2.f * r.y * r.y;   // <D_i, D_i>
                float Sii = DD * (1.f / (Bf * Bf)) - (2.f / Bf) * r.w + gi * gi;
                sq[i] = sqrtf(sqrtf(fmaxf(Sii, 0.f)));
            }
        } else {
            // ---- triplet partial ----
            float* red = (float*)dt;
            const int tt = (pb - F_) * 512 + t;     // 0..1023
            int a = trip[3 * tt]     & (B_ - 1);
            int p = trip[3 * tt + 1] & (B_ - 1);
            int n = trip[3 * tt + 2] & (B_ - 1);
            const float4* ea = (const float4*)(emb + a * F_);
            const float4* ep = (const float4*)(emb + p * F_);
            const float4* en = (const float4*)(emb + n * F_);
            float ap = 0.f, an = 0.f;
            #pragma unroll 8
            for (int f4 = 0; f4 < F_ / 4; ++f4) {
                float4 va = ea[f4], vp = ep[f4], vn = en[f4];
                float d;
                d = va.x - vp.x; ap = fmaf(d, d, ap);
                d = va.y - vp.y; ap = fmaf(d, d, ap);
                d = va.z - vp.z; ap = fmaf(d, d, ap);
                d = va.w - vp.w; ap = fmaf(d, d, ap);
                d = va.x - vn.x; an = fmaf(d, d, an);
                d = va.y - vn.y; an = fmaf(d, d, an);
                d = va.z - vn.z; an = fmaf(d, d, an);
                d = va.w - vn.w; an = fmaf(d, d, an);
            }
            float l = fmaxf(ap - an + MARGIN, 0.f);
            red[t] = l;
            __syncthreads();
            for (int sh = 256; sh > 0; sh >>= 1) {
                if (t < sh) red[t] += red[t + sh];
                __syncthreads();
            }
            if (t == 0) tl[pb - F_] = red[0];
        }
        return;
    }

    // ---------------- pair GEMM: 2 phases ----------------
    const int pb = bid;                 // pair-block id 0..527
    int ba = 0, rem = pb;
    while (rem >= NBLK - ba) { rem -= NBLK - ba; ++ba; }
    const int bb = ba + rem;
    const bool diag = (ba == bb);

    const int lane = t & 63;
    const int w    = t >> 6;
    const int wr   = w >> 1;          // 0..3: row-groups {2wr, 2wr+1}
    const int wc   = w & 1;           // 0..1: col-groups {4wc .. 4wc+3}
    const int i    = t & 127;         // feature (d-gen)
    const int pg   = t >> 7;          // 0..3: chunk / a-subrange
    const int fr_row = lane & 15;
    const int fr_k4  = (lane >> 4) * 4;

    f32x4 acc[2][4];
    #pragma unroll
    for (int q = 0; q < 2; ++q)
        #pragma unroll
        for (int c = 0; c < 4; ++c) acc[q][c] = (f32x4)(0.f);

    float xb[16];
    #pragma unroll
    for (int b = 0; b < 16; ++b) xb[b] = emb[(bb * 16 + b) * F_ + i];

    #pragma unroll
    for (int h = 0; h < 2; ++h) {
        const float xa0 = emb[(ba * 16 + h * 8 + pg * 2 + 0) * F_ + i];
        const float xa1 = emb[(ba * 16 + h * 8 + pg * 2 + 1) * F_ + i];
        if (h) __syncthreads();           // phase-0 reads done before restage
        #pragma unroll
        for (int ar2 = 0; ar2 < 2; ++ar2) {
            const float xa = ar2 ? xa1 : xa0;
            const int pa = h * 8 + pg * 2 + ar2;
            unsigned int pk[8];
            #pragma unroll
            for (int q = 0; q < 8; ++q) {
                float d0 = fabsf(xa - xb[2 * q]);
                float d1 = fabsf(xa - xb[2 * q + 1]);
                if (diag && pa >= 2 * q)     d0 = 0.f;
                if (diag && pa >= 2 * q + 1) d1 = 0.f;
                pk[q] = bf16r(d0) | (bf16r(d1) << 16);
            }
            unsigned int* dst = &dt[pg * (F_ * LDS_ROW) + i * LDS_ROW + ar2 * 8];
            *reinterpret_cast<uint4*>(dst)     = make_uint4(pk[0], pk[1], pk[2], pk[3]);
            *reinterpret_cast<uint4*>(dst + 4) = make_uint4(pk[4], pk[5], pk[6], pk[7]);
        }
        __syncthreads();
        #pragma unroll
        for (int c = 0; c < 4; ++c) {     // K-chunks of 32 pairs
            const unsigned int* base = &dt[c * (F_ * LDS_ROW)];
            const bf16x8 fA0 = *reinterpret_cast<const bf16x8*>(
                &base[((wr * 2 + 0) * 16 + fr_row) * LDS_ROW + fr_k4]);
            const bf16x8 fA1 = *reinterpret_cast<const bf16x8*>(
                &base[((wr * 2 + 1) * 16 + fr_row) * LDS_ROW + fr_k4]);
            #pragma unroll
            for (int cg = 0; cg < 4; ++cg) {
                const bf16x8 fB = *reinterpret_cast<const bf16x8*>(
                    &base[((wc * 4 + cg) * 16 + fr_row) * LDS_ROW + fr_k4]);
                acc[0][cg] = __builtin_amdgcn_mfma_f32_16x16x32_bf16(fA0, fB, acc[0][cg], 0, 0, 0);
                acc[1][cg] = __builtin_amdgcn_mfma_f32_16x16x32_bf16(fA1, fB, acc[1][cg], 0, 0, 0);
            }
        }
    }

    // ---- epilogue: stage C in LDS, then coalesced nontemporal stores ----
    __syncthreads();                     // all dt reads complete
    unsigned short* sl = (unsigned short*)dt;     // [128][SL_ROW] = 34.8 KB
    const int cj = lane & 15;
    const int rsub = (lane >> 4) * 4;
    #pragma unroll
    for (int q = 0; q < 2; ++q)
        #pragma unroll
        for (int cg = 0; cg < 4; ++cg)
            #pragma unroll
            for (int r = 0; r < 4; ++r)
                sl[((wr * 2 + q) * 16 + rsub + r) * SL_ROW + (wc * 4 + cg) * 16 + cj] =
                    (unsigned short)bf16r(acc[q][cg][r]);
    __syncthreads();
    {   // thread t: slab row t>>2, 32-ushort chunk (t&3) — 64 contiguous bytes
        const unsigned short* s = &sl[(t >> 2) * SL_ROW + (t & 3) * 32];
        unsigned short* dp = part + (size_t)pb * (F_ * F_) + (t >> 2) * F_ + (t & 3) * 32;
        #pragma unroll
        for (int k = 0; k < 4; ++k) {
            u32x4 v = *reinterpret_cast<const u32x4*>(s + k * 8);
            __builtin_nontemporal_store(v, reinterpret_cast<u32x4*>(dp + k * 8));
        }
    }
}

// ===== K2: 256 blocks; block -> half S-row + corr partial -> atomicAdd =====
// i = bid>>1, jh = bid&1 (j in [jh*64, jh*64+64))
__global__ __launch_bounds__(512)
void k2_srow_final(const unsigned short* __restrict__ part,
                   const float* __restrict__ m, const float* __restrict__ mT,
                   const float* __restrict__ g, const float* __restrict__ sq,
                   const float* __restrict__ tl, float* __restrict__ out) {
    __shared__ float shT[16][64];     // 4 KB: T slices
    __shared__ float shM[8][64];      // 2 KB: md slices
    __shared__ float smi[B_];         // 2 KB: m row i
    __shared__ float red[64];
    const int bid = blockIdx.x;
    const int i   = bid >> 1;
    const int jh  = bid & 1;
    const int t   = threadIdx.x;

    // ---- T[j] over 528 slabs: 16 slices x 33, 128 B coalesced chunks ----
    const int dw = t & 31;            // dword within half-row (2 j's per dword)
    const int sl = t >> 5;            // 0..15
    const unsigned int* src = reinterpret_cast<const unsigned int*>(part)
                            + i * 64 + jh * 32 + dw;
    float tlo = 0.f, thi = 0.f;
    #pragma unroll 11
    for (int s = sl * 33; s < sl * 33 + 33; ++s) {
        unsigned int v = src[(size_t)s * 8192];
        tlo += __uint_as_float(v << 16);
        thi += __uint_as_float(v & 0xFFFF0000u);
    }
    shT[sl][dw * 2]     = tlo;
    shT[sl][dw * 2 + 1] = thi;
    smi[t] = m[i * B_ + t];
    __syncthreads();

    // ---- md[j] = <m_i, m_j>: 8 slices of 64 a's, mT coalesced ----
    const int jl = t & 63;
    const int j  = jh * 64 + jl;
    const int q8 = t >> 6;            // 0..7
    float md = 0.f;
    const float* mta = mT + (size_t)(q8 * 64) * F_ + j;
    const float* mia = smi + q8 * 64;
    #pragma unroll 8
    for (int a = 0; a < 64; ++a) md = fmaf(mia[a], mta[(size_t)a * F_], md);
    shM[q8][jl] = md;
    __syncthreads();

    if (t < 64) {
        float T = 0.f;
        #pragma unroll
        for (int s = 0; s < 16; ++s) T += shT[s][t];
        float mdj = 0.f;
        #pragma unroll
        for (int s = 0; s < 8; ++s) mdj += shM[s][t];
        const int jj = jh * 64 + t;
        float Sij = 2.f * T * (1.f / ((float)B_ * (float)B_))
                  - (2.f / (float)B_) * mdj
                  + g[i] * g[jj];
        float c = 0.f;
        if (jj > i) c = sqrtf(fmaxf(Sij, 0.f)) / (sq[i] * sq[jj]);
        red[t] = c;
    }
    __syncthreads();
    for (int sh = 32; sh > 0; sh >>= 1) {
        if (t < sh) red[t] += red[t + sh];
        __syncthreads();
    }
    if (t == 0) {
        float v = red[0] * (1.f / 8128.f);
        if (bid == 0) v += (tl[0] + tl[1]) * (1.f / (float)NTRIP);
        atomicAdd(out, v);
    }
}

extern "C" void kernel_launch(void* const* d_in, const int* in_sizes, int n_in,
                              void* d_out, int out_size, void* d_ws, size_t ws_size,
                              hipStream_t stream) {
    const float* emb = (const float*)d_in[0];
    const int*   trp = (const int*)d_in[1];
    float* ws  = (float*)d_ws;
    float* m   = ws + OFF_M;
    float* mT  = ws + OFF_MT;
    float* g   = ws + OFF_G;
    float* tl  = ws + OFF_TL;
    float* sq  = ws + OFF_SQ;
    unsigned short* part = (unsigned short*)(ws + OFF_PART);
    float* out = (float*)d_out;

    k1_prep_pair  <<<NPB + PREP, 512, 0, stream>>>(emb, trp, m, mT, g, tl, sq, out, part);
    k2_srow_final <<<256, 512, 0, stream>>>(part, m, mT, g, sq, tl, out);
}

// Round 11
// 50.205 us; speedup vs baseline: 1.1810x; 1.1810x over previous
//
#include <hip/hip_runtime.h>
#include <hip/hip_bf16.h>

#define B_    512
#define F_    128
#define NTRIP 1024
#define MARGIN 1.0f
#define NBLK  32      // 512/16 pair-blocks per dim
#define NPB   528     // upper-tri pair-blocks
#define PREP  130     // prep blocks: 128 m/g + 2 triplet

// ws layout (float offsets)
#define OFF_M    0                 // m  [128][512]
#define OFF_MT   65536             // mT [512][128]
#define OFF_G    131072            // g  [128]
#define OFF_TL   131200            // tl [2]
#define OFF_SQ   131216            // sq [128] = sqrt(sqrt(S_ii))
#define OFF_PART 147600            // ushort[528*16384] (17.3 MB)

typedef __attribute__((ext_vector_type(8))) short bf16x8;
typedef __attribute__((ext_vector_type(4))) float f32x4;
typedef __attribute__((ext_vector_type(4))) unsigned int u32x4;

#define LDS_ROW 20    // dwords per 32-pair row: 16 + 4 pad (80 B) — 0-conflict
#define SL_ROW  136   // ushorts per slab-stage row (272 B, 16B-aligned)

__device__ inline unsigned int bf16r(float f) {   // RNE float->bf16 (f>=0, finite)
    unsigned int u = __float_as_uint(f);
    u += 0x7FFFu + ((u >> 16) & 1u);
    return u >> 16;
}

// ===== K1: blocks 0..527 pair GEMM; 528..657 prep (m/mT/g/sq/triplet) ======
__global__ __launch_bounds__(512)
void k1_prep_pair(const float* __restrict__ emb, const int* __restrict__ trip,
                  float* __restrict__ m, float* __restrict__ mT,
                  float* __restrict__ g, float* __restrict__ tl,
                  float* __restrict__ sq, float* __restrict__ out,
                  unsigned short* __restrict__ part) {
    __shared__ __align__(16) unsigned int dt[4 * F_ * LDS_ROW];   // 40 KB
    const int bid = blockIdx.x;
    const int t   = threadIdx.x;

    if (bid >= NPB) {
        const int pb = bid - NPB;
        if (pb < F_) {
            // ---- m/g/sq for feature i ----
            float*  x    = (float*)dt;                    // [512]
            float4* red4 = (float4*)((float*)dt + 512);   // [512] (8 KB)
            const int i = pb;
            if (i == 0 && t == 0) out[0] = 0.f;           // reset accumulator
            x[t] = emb[t * F_ + i];
            __syncthreads();
            const float xa = x[t];
            float s0 = 0.f, s1 = 0.f, s2 = 0.f, s3 = 0.f;
            for (int b = 0; b < B_; b += 4) {
                s0 += fabsf(xa - x[b]);
                s1 += fabsf(xa - x[b + 1]);
                s2 += fabsf(xa - x[b + 2]);
                s3 += fabsf(xa - x[b + 3]);
            }
            float s = (s0 + s1) + (s2 + s3);
            float mv = s * (1.f / B_);
            m[i * B_ + t]  = mv;
            mT[t * F_ + i] = mv;
            red4[t] = make_float4(s, xa, xa * xa, mv * mv);
            __syncthreads();
            for (int sh = 256; sh > 0; sh >>= 1) {
                if (t < sh) {
                    float4 a = red4[t], b = red4[t + sh];
                    red4[t] = make_float4(a.x + b.x, a.y + b.y, a.z + b.z, a.w + b.w);
                }
                __syncthreads();
            }
            if (t == 0) {
                float4 r = red4[0];
                const float Bf = (float)B_;
                float gi = r.x * (1.f / (Bf * Bf));
                g[i] = gi;
                float DD  = 2.f * Bf * r.z - 2.f * r.y * r.y;   // <D_i, D_i>
                float Sii = DD * (1.f / (Bf * Bf)) - (2.f / Bf) * r.w + gi * gi;
                sq[i] = sqrtf(sqrtf(fmaxf(Sii, 0.f)));
            }
        } else {
            // ---- triplet partial ----
            float* red = (float*)dt;
            const int tt = (pb - F_) * 512 + t;     // 0..1023
            int a = trip[3 * tt]     & (B_ - 1);
            int p = trip[3 * tt + 1] & (B_ - 1);
            int n = trip[3 * tt + 2] & (B_ - 1);
            const float4* ea = (const float4*)(emb + a * F_);
            const float4* ep = (const float4*)(emb + p * F_);
            const float4* en = (const float4*)(emb + n * F_);
            float ap = 0.f, an = 0.f;
            #pragma unroll 8
            for (int f4 = 0; f4 < F_ / 4; ++f4) {
                float4 va = ea[f4], vp = ep[f4], vn = en[f4];
                float d;
                d = va.x - vp.x; ap = fmaf(d, d, ap);
                d = va.y - vp.y; ap = fmaf(d, d, ap);
                d = va.z - vp.z; ap = fmaf(d, d, ap);
                d = va.w - vp.w; ap = fmaf(d, d, ap);
                d = va.x - vn.x; an = fmaf(d, d, an);
                d = va.y - vn.y; an = fmaf(d, d, an);
                d = va.z - vn.z; an = fmaf(d, d, an);
                d = va.w - vn.w; an = fmaf(d, d, an);
            }
            float l = fmaxf(ap - an + MARGIN, 0.f);
            red[t] = l;
            __syncthreads();
            for (int sh = 256; sh > 0; sh >>= 1) {
                if (t < sh) red[t] += red[t + sh];
                __syncthreads();
            }
            if (t == 0) tl[pb - F_] = red[0];
        }
        return;
    }

    // ---------------- pair GEMM: 2 phases ----------------
    const int pb = bid;                 // pair-block id 0..527
    int ba = 0, rem = pb;
    while (rem >= NBLK - ba) { rem -= NBLK - ba; ++ba; }
    const int bb = ba + rem;
    const bool diag = (ba == bb);

    const int lane = t & 63;
    const int w    = t >> 6;
    const int wr   = w >> 1;          // 0..3: row-groups {2wr, 2wr+1}
    const int wc   = w & 1;           // 0..1: col-groups {4wc .. 4wc+3}
    const int i    = t & 127;         // feature (d-gen)
    const int pg   = t >> 7;          // 0..3: chunk / a-subrange
    const int fr_row = lane & 15;
    const int fr_k4  = (lane >> 4) * 4;

    f32x4 acc[2][4];
    #pragma unroll
    for (int q = 0; q < 2; ++q)
        #pragma unroll
        for (int c = 0; c < 4; ++c) acc[q][c] = (f32x4)(0.f);

    float xb[16];
    #pragma unroll
    for (int b = 0; b < 16; ++b) xb[b] = emb[(bb * 16 + b) * F_ + i];

    #pragma unroll
    for (int h = 0; h < 2; ++h) {
        const float xa0 = emb[(ba * 16 + h * 8 + pg * 2 + 0) * F_ + i];
        const float xa1 = emb[(ba * 16 + h * 8 + pg * 2 + 1) * F_ + i];
        if (h) __syncthreads();           // phase-0 reads done before restage
        #pragma unroll
        for (int ar2 = 0; ar2 < 2; ++ar2) {
            const float xa = ar2 ? xa1 : xa0;
            const int pa = h * 8 + pg * 2 + ar2;
            unsigned int pk[8];
            #pragma unroll
            for (int q = 0; q < 8; ++q) {
                float d0 = fabsf(xa - xb[2 * q]);
                float d1 = fabsf(xa - xb[2 * q + 1]);
                if (diag && pa >= 2 * q)     d0 = 0.f;
                if (diag && pa >= 2 * q + 1) d1 = 0.f;
                pk[q] = bf16r(d0) | (bf16r(d1) << 16);
            }
            unsigned int* dst = &dt[pg * (F_ * LDS_ROW) + i * LDS_ROW + ar2 * 8];
            *reinterpret_cast<uint4*>(dst)     = make_uint4(pk[0], pk[1], pk[2], pk[3]);
            *reinterpret_cast<uint4*>(dst + 4) = make_uint4(pk[4], pk[5], pk[6], pk[7]);
        }
        __syncthreads();
        #pragma unroll
        for (int c = 0; c < 4; ++c) {     // K-chunks of 32 pairs
            const unsigned int* base = &dt[c * (F_ * LDS_ROW)];
            const bf16x8 fA0 = *reinterpret_cast<const bf16x8*>(
                &base[((wr * 2 + 0) * 16 + fr_row) * LDS_ROW + fr_k4]);
            const bf16x8 fA1 = *reinterpret_cast<const bf16x8*>(
                &base[((wr * 2 + 1) * 16 + fr_row) * LDS_ROW + fr_k4]);
            #pragma unroll
            for (int cg = 0; cg < 4; ++cg) {
                const bf16x8 fB = *reinterpret_cast<const bf16x8*>(
                    &base[((wc * 4 + cg) * 16 + fr_row) * LDS_ROW + fr_k4]);
                acc[0][cg] = __builtin_amdgcn_mfma_f32_16x16x32_bf16(fA0, fB, acc[0][cg], 0, 0, 0);
                acc[1][cg] = __builtin_amdgcn_mfma_f32_16x16x32_bf16(fA1, fB, acc[1][cg], 0, 0, 0);
            }
        }
    }

    // ---- epilogue: stage C in LDS, then coalesced (L2 write-back) stores ----
    __syncthreads();                     // all dt reads complete
    unsigned short* sl = (unsigned short*)dt;     // [128][SL_ROW] = 34.8 KB
    const int cj = lane & 15;
    const int rsub = (lane >> 4) * 4;
    #pragma unroll
    for (int q = 0; q < 2; ++q)
        #pragma unroll
        for (int cg = 0; cg < 4; ++cg)
            #pragma unroll
            for (int r = 0; r < 4; ++r)
                sl[((wr * 2 + q) * 16 + rsub + r) * SL_ROW + (wc * 4 + cg) * 16 + cj] =
                    (unsigned short)bf16r(acc[q][cg][r]);
    __syncthreads();
    {   // thread t: slab row t>>2, 32-ushort chunk (t&3) — 64 contiguous bytes
        const unsigned short* s = &sl[(t >> 2) * SL_ROW + (t & 3) * 32];
        unsigned short* dp = part + (size_t)pb * (F_ * F_) + (t >> 2) * F_ + (t & 3) * 32;
        #pragma unroll
        for (int k = 0; k < 4; ++k) {
            u32x4 v = *reinterpret_cast<const u32x4*>(s + k * 8);
            *reinterpret_cast<u32x4*>(dp + k * 8) = v;
        }
    }
}

// ===== K2: 256 blocks; block -> half S-row + corr partial -> atomicAdd =====
// i = bid>>1, jh = bid&1 (j in [jh*64, jh*64+64))
__global__ __launch_bounds__(512)
void k2_srow_final(const unsigned short* __restrict__ part,
                   const float* __restrict__ m, const float* __restrict__ mT,
                   const float* __restrict__ g, const float* __restrict__ sq,
                   const float* __restrict__ tl, float* __restrict__ out) {
    __shared__ float shT[16][64];     // 4 KB: T slices
    __shared__ float shM[8][64];      // 2 KB: md slices
    __shared__ float smi[B_];         // 2 KB: m row i
    __shared__ float red[64];
    const int bid = blockIdx.x;
    const int i   = bid >> 1;
    const int jh  = bid & 1;
    const int t   = threadIdx.x;

    // ---- T[j] over 528 slabs: 16 slices x 33, 128 B coalesced chunks ----
    const int dw = t & 31;            // dword within half-row (2 j's per dword)
    const int sl = t >> 5;            // 0..15
    const unsigned int* src = reinterpret_cast<const unsigned int*>(part)
                            + i * 64 + jh * 32 + dw;
    float tlo = 0.f, thi = 0.f;
    #pragma unroll 11
    for (int s = sl * 33; s < sl * 33 + 33; ++s) {
        unsigned int v = src[(size_t)s * 8192];
        tlo += __uint_as_float(v << 16);
        thi += __uint_as_float(v & 0xFFFF0000u);
    }
    shT[sl][dw * 2]     = tlo;
    shT[sl][dw * 2 + 1] = thi;
    smi[t] = m[i * B_ + t];
    __syncthreads();

    // ---- md[j] = <m_i, m_j>: 8 slices of 64 a's, mT coalesced ----
    const int jl = t & 63;
    const int j  = jh * 64 + jl;
    const int q8 = t >> 6;            // 0..7
    float md = 0.f;
    const float* mta = mT + (size_t)(q8 * 64) * F_ + j;
    const float* mia = smi + q8 * 64;
    #pragma unroll 8
    for (int a = 0; a < 64; ++a) md = fmaf(mia[a], mta[(size_t)a * F_], md);
    shM[q8][jl] = md;
    __syncthreads();

    if (t < 64) {
        float T = 0.f;
        #pragma unroll
        for (int s = 0; s < 16; ++s) T += shT[s][t];
        float mdj = 0.f;
        #pragma unroll
        for (int s = 0; s < 8; ++s) mdj += shM[s][t];
        const int jj = jh * 64 + t;
        float Sij = 2.f * T * (1.f / ((float)B_ * (float)B_))
                  - (2.f / (float)B_) * mdj
                  + g[i] * g[jj];
        float c = 0.f;
        if (jj > i) c = sqrtf(fmaxf(Sij, 0.f)) / (sq[i] * sq[jj]);
        red[t] = c;
    }
    __syncthreads();
    for (int sh = 32; sh > 0; sh >>= 1) {
        if (t < sh) red[t] += red[t + sh];
        __syncthreads();
    }
    if (t == 0) {
        float v = red[0] * (1.f / 8128.f);
        if (bid == 0) v += (tl[0] + tl[1]) * (1.f / (float)NTRIP);
        atomicAdd(out, v);
    }
}

extern "C" void kernel_launch(void* const* d_in, const int* in_sizes, int n_in,
                              void* d_out, int out_size, void* d_ws, size_t ws_size,
                              hipStream_t stream) {
    const float* emb = (const float*)d_in[0];
    const int*   trp = (const int*)d_in[1];
    float* ws  = (float*)d_ws;
    float* m   = ws + OFF_M;
    float* mT  = ws + OFF_MT;
    float* g   = ws + OFF_G;
    float* tl  = ws + OFF_TL;
    float* sq  = ws + OFF_SQ;
    unsigned short* part = (unsigned short*)(ws + OFF_PART);
    float* out = (float*)d_out;

    k1_prep_pair  <<<NPB + PREP, 512, 0, stream>>>(emb, trp, m, mT, g, tl, sq, out, part);
    k2_srow_final <<<256, 512, 0, stream>>>(part, m, mT, g, sq, tl, out);
}

// Round 12
// 38.606 us; speedup vs baseline: 1.5358x; 1.3005x over previous
//
#include <hip/hip_runtime.h>
#include <hip/hip_bf16.h>

#define B_    512
#define F_    128
#define NTRIP 1024
#define MARGIN 1.0f
#define NBLK  32      // 512/16 pair-blocks per dim
#define NPAIRB 132    // pair GEMM blocks; each folds 4 pair-units
#define NFOLD  4      // units per block: L = pb + u*NPAIRB, 4*132 = 528
#define PREP  130     // prep blocks: 128 m/g + 2 triplet

// ws layout (float offsets)
#define OFF_M    0                 // m  [128][512]
#define OFF_MT   65536             // mT [512][128]
#define OFF_G    131072            // g  [128]
#define OFF_TL   131200            // tl [2]
#define OFF_SQ   131216            // sq [128] = sqrt(sqrt(S_ii))
#define OFF_PART 147600            // ushort[132*16384] (4.3 MB)

typedef __attribute__((ext_vector_type(8))) short bf16x8;
typedef __attribute__((ext_vector_type(4))) float f32x4;

#define LDS_ROW 20    // dwords per 32-pair row: 16 + 4 pad (80 B) — 0-conflict

__device__ inline unsigned int bf16r(float f) {   // RNE float->bf16 (f>=0, finite)
    unsigned int u = __float_as_uint(f);
    u += 0x7FFFu + ((u >> 16) & 1u);
    return u >> 16;
}

// ===== K1: blocks 0..129 prep (m/mT/g/sq/triplet); 130..261 pair GEMM ======
__global__ __launch_bounds__(512)
void k1_prep_pair(const float* __restrict__ emb, const int* __restrict__ trip,
                  float* __restrict__ m, float* __restrict__ mT,
                  float* __restrict__ g, float* __restrict__ tl,
                  float* __restrict__ sq, float* __restrict__ out,
                  unsigned short* __restrict__ part) {
    __shared__ __align__(16) unsigned int dt[4 * F_ * LDS_ROW];   // 40 KB
    const int bid = blockIdx.x;
    const int t   = threadIdx.x;

    if (bid < PREP) {
        if (bid < F_) {
            // ---- m/g/sq for feature i ----
            float*  x    = (float*)dt;                    // [512]
            float4* red4 = (float4*)((float*)dt + 512);   // [512] (8 KB)
            const int i = bid;
            if (i == 0 && t == 0) out[0] = 0.f;           // reset accumulator
            x[t] = emb[t * F_ + i];
            __syncthreads();
            const float xa = x[t];
            float s0 = 0.f, s1 = 0.f, s2 = 0.f, s3 = 0.f;
            for (int b = 0; b < B_; b += 4) {
                s0 += fabsf(xa - x[b]);
                s1 += fabsf(xa - x[b + 1]);
                s2 += fabsf(xa - x[b + 2]);
                s3 += fabsf(xa - x[b + 3]);
            }
            float s = (s0 + s1) + (s2 + s3);
            float mv = s * (1.f / B_);
            m[i * B_ + t]  = mv;
            mT[t * F_ + i] = mv;
            red4[t] = make_float4(s, xa, xa * xa, mv * mv);
            __syncthreads();
            for (int sh = 256; sh > 0; sh >>= 1) {
                if (t < sh) {
                    float4 a = red4[t], b = red4[t + sh];
                    red4[t] = make_float4(a.x + b.x, a.y + b.y, a.z + b.z, a.w + b.w);
                }
                __syncthreads();
            }
            if (t == 0) {
                float4 r = red4[0];
                const float Bf = (float)B_;
                float gi = r.x * (1.f / (Bf * Bf));
                g[i] = gi;
                float DD  = 2.f * Bf * r.z - 2.f * r.y * r.y;   // <D_i, D_i>
                float Sii = DD * (1.f / (Bf * Bf)) - (2.f / Bf) * r.w + gi * gi;
                sq[i] = sqrtf(sqrtf(fmaxf(Sii, 0.f)));
            }
        } else {
            // ---- triplet partial ----
            float* red = (float*)dt;
            const int tt = (bid - F_) * 512 + t;     // 0..1023
            int a = trip[3 * tt]     & (B_ - 1);
            int p = trip[3 * tt + 1] & (B_ - 1);
            int n = trip[3 * tt + 2] & (B_ - 1);
            const float4* ea = (const float4*)(emb + a * F_);
            const float4* ep = (const float4*)(emb + p * F_);
            const float4* en = (const float4*)(emb + n * F_);
            float ap = 0.f, an = 0.f;
            #pragma unroll 8
            for (int f4 = 0; f4 < F_ / 4; ++f4) {
                float4 va = ea[f4], vp = ep[f4], vn = en[f4];
                float d;
                d = va.x - vp.x; ap = fmaf(d, d, ap);
                d = va.y - vp.y; ap = fmaf(d, d, ap);
                d = va.z - vp.z; ap = fmaf(d, d, ap);
                d = va.w - vp.w; ap = fmaf(d, d, ap);
                d = va.x - vn.x; an = fmaf(d, d, an);
                d = va.y - vn.y; an = fmaf(d, d, an);
                d = va.z - vn.z; an = fmaf(d, d, an);
                d = va.w - vn.w; an = fmaf(d, d, an);
            }
            float l = fmaxf(ap - an + MARGIN, 0.f);
            red[t] = l;
            __syncthreads();
            for (int sh = 256; sh > 0; sh >>= 1) {
                if (t < sh) red[t] += red[t + sh];
                __syncthreads();
            }
            if (t == 0) tl[bid - F_] = red[0];
        }
        return;
    }

    // -------- pair GEMM: fold 4 pair-units into one 128x128 T tile --------
    const int pbp = bid - PREP;         // 0..131
    const int lane = t & 63;
    const int w    = t >> 6;
    const int wr   = w >> 1;          // 0..3: row-groups {2wr, 2wr+1}
    const int wc   = w & 1;           // 0..1: col-groups {4wc .. 4wc+3}
    const int i    = t & 127;         // feature (d-gen)
    const int pg   = t >> 7;          // 0..3: chunk / a-subrange
    const int fr_row = lane & 15;
    const int fr_k4  = (lane >> 4) * 4;

    f32x4 acc[2][4];
    #pragma unroll
    for (int q = 0; q < 2; ++q)
        #pragma unroll
        for (int c = 0; c < 4; ++c) acc[q][c] = (f32x4)(0.f);

    for (int u = 0; u < NFOLD; ++u) {
        const int L = pbp + u * NPAIRB;     // pair-unit id 0..527
        int ba = 0, rem = L;
        while (rem >= NBLK - ba) { rem -= NBLK - ba; ++ba; }
        const int bb = ba + rem;
        const bool diag = (ba == bb);

        float xb[16];
        #pragma unroll
        for (int b = 0; b < 16; ++b) xb[b] = emb[(bb * 16 + b) * F_ + i];

        #pragma unroll
        for (int h = 0; h < 2; ++h) {
            const float xa0 = emb[(ba * 16 + h * 8 + pg * 2 + 0) * F_ + i];
            const float xa1 = emb[(ba * 16 + h * 8 + pg * 2 + 1) * F_ + i];
            if (h | u) __syncthreads();       // prior-phase reads done before restage
            #pragma unroll
            for (int ar2 = 0; ar2 < 2; ++ar2) {
                const float xa = ar2 ? xa1 : xa0;
                const int pa = h * 8 + pg * 2 + ar2;
                unsigned int pk[8];
                #pragma unroll
                for (int q = 0; q < 8; ++q) {
                    float d0 = fabsf(xa - xb[2 * q]);
                    float d1 = fabsf(xa - xb[2 * q + 1]);
                    if (diag && pa >= 2 * q)     d0 = 0.f;
                    if (diag && pa >= 2 * q + 1) d1 = 0.f;
                    pk[q] = bf16r(d0) | (bf16r(d1) << 16);
                }
                unsigned int* dst = &dt[pg * (F_ * LDS_ROW) + i * LDS_ROW + ar2 * 8];
                *reinterpret_cast<uint4*>(dst)     = make_uint4(pk[0], pk[1], pk[2], pk[3]);
                *reinterpret_cast<uint4*>(dst + 4) = make_uint4(pk[4], pk[5], pk[6], pk[7]);
            }
            __syncthreads();
            #pragma unroll
            for (int c = 0; c < 4; ++c) {     // K-chunks of 32 pairs
                const unsigned int* base = &dt[c * (F_ * LDS_ROW)];
                const bf16x8 fA0 = *reinterpret_cast<const bf16x8*>(
                    &base[((wr * 2 + 0) * 16 + fr_row) * LDS_ROW + fr_k4]);
                const bf16x8 fA1 = *reinterpret_cast<const bf16x8*>(
                    &base[((wr * 2 + 1) * 16 + fr_row) * LDS_ROW + fr_k4]);
                #pragma unroll
                for (int cg = 0; cg < 4; ++cg) {
                    const bf16x8 fB = *reinterpret_cast<const bf16x8*>(
                        &base[((wc * 4 + cg) * 16 + fr_row) * LDS_ROW + fr_k4]);
                    acc[0][cg] = __builtin_amdgcn_mfma_f32_16x16x32_bf16(fA0, fB, acc[0][cg], 0, 0, 0);
                    acc[1][cg] = __builtin_amdgcn_mfma_f32_16x16x32_bf16(fA1, fB, acc[1][cg], 0, 0, 0);
                }
            }
        }
    }

    // epilogue -> bf16 slab; C layout: col=lane&15, row=(lane>>4)*4+reg
    unsigned short* dstp = part + (size_t)pbp * (F_ * F_);
    const int cj = lane & 15;
    const int rsub = (lane >> 4) * 4;
    #pragma unroll
    for (int q = 0; q < 2; ++q)
        #pragma unroll
        for (int cg = 0; cg < 4; ++cg)
            #pragma unroll
            for (int r = 0; r < 4; ++r)
                dstp[((wr * 2 + q) * 16 + rsub + r) * F_ + (wc * 4 + cg) * 16 + cj] =
                    (unsigned short)bf16r(acc[q][cg][r]);
}

// ===== K2: 256 blocks; block -> half S-row + corr partial -> atomicAdd =====
// i = bid>>1, jh = bid&1 (j in [jh*64, jh*64+64))
__global__ __launch_bounds__(512)
void k2_srow_final(const unsigned short* __restrict__ part,
                   const float* __restrict__ m, const float* __restrict__ mT,
                   const float* __restrict__ g, const float* __restrict__ sq,
                   const float* __restrict__ tl, float* __restrict__ out) {
    __shared__ float shT[16][64];     // 4 KB: T slices
    __shared__ float shM[8][64];      // 2 KB: md slices
    __shared__ float smi[B_];         // 2 KB: m row i
    __shared__ float red[64];
    const int bid = blockIdx.x;
    const int i   = bid >> 1;
    const int jh  = bid & 1;
    const int t   = threadIdx.x;

    // ---- T[j] over 132 slabs: 16 slices (9/9/9/9 then 8x12), coalesced ----
    const int dw = t & 31;            // dword within half-row (2 j's per dword)
    const int sl = t >> 5;            // 0..15
    const int cnt = (sl < 4) ? 9 : 8;
    const int st  = sl * 8 + (sl < 4 ? sl : 4);
    const unsigned int* src = reinterpret_cast<const unsigned int*>(part)
                            + i * 64 + jh * 32 + dw;
    float tlo = 0.f, thi = 0.f;
    for (int s = st; s < st + cnt; ++s) {
        unsigned int v = src[(size_t)s * 8192];
        tlo += __uint_as_float(v << 16);
        thi += __uint_as_float(v & 0xFFFF0000u);
    }
    shT[sl][dw * 2]     = tlo;
    shT[sl][dw * 2 + 1] = thi;
    smi[t] = m[i * B_ + t];
    __syncthreads();

    // ---- md[j] = <m_i, m_j>: 8 slices of 64 a's, mT coalesced ----
    const int jl = t & 63;
    const int j  = jh * 64 + jl;
    const int q8 = t >> 6;            // 0..7
    float md = 0.f;
    const float* mta = mT + (size_t)(q8 * 64) * F_ + j;
    const float* mia = smi + q8 * 64;
    #pragma unroll 8
    for (int a = 0; a < 64; ++a) md = fmaf(mia[a], mta[(size_t)a * F_], md);
    shM[q8][jl] = md;
    __syncthreads();

    if (t < 64) {
        float T = 0.f;
        #pragma unroll
        for (int s = 0; s < 16; ++s) T += shT[s][t];
        float mdj = 0.f;
        #pragma unroll
        for (int s = 0; s < 8; ++s) mdj += shM[s][t];
        const int jj = jh * 64 + t;
        float Sij = 2.f * T * (1.f / ((float)B_ * (float)B_))
                  - (2.f / (float)B_) * mdj
                  + g[i] * g[jj];
        float c = 0.f;
        if (jj > i) c = sqrtf(fmaxf(Sij, 0.f)) / (sq[i] * sq[jj]);
        red[t] = c;
    }
    __syncthreads();
    for (int sh = 32; sh > 0; sh >>= 1) {
        if (t < sh) red[t] += red[t + sh];
        __syncthreads();
    }
    if (t == 0) {
        float v = red[0] * (1.f / 8128.f);
        if (bid == 0) v += (tl[0] + tl[1]) * (1.f / (float)NTRIP);
        atomicAdd(out, v);
    }
}

extern "C" void kernel_launch(void* const* d_in, const int* in_sizes, int n_in,
                              void* d_out, int out_size, void* d_ws, size_t ws_size,
                              hipStream_t stream) {
    const float* emb = (const float*)d_in[0];
    const int*   trp = (const int*)d_in[1];
    float* ws  = (float*)d_ws;
    float* m   = ws + OFF_M;
    float* mT  = ws + OFF_MT;
    float* g   = ws + OFF_G;
    float* tl  = ws + OFF_TL;
    float* sq  = ws + OFF_SQ;
    unsigned short* part = (unsigned short*)(ws + OFF_PART);
    float* out = (float*)d_out;

    k1_prep_pair  <<<PREP + NPAIRB, 512, 0, stream>>>(emb, trp, m, mT, g, tl, sq, out, part);
    k2_srow_final <<<256, 512, 0, stream>>>(part, m, mT, g, sq, tl, out);
}